// Round 1
// 384.561 us; speedup vs baseline: 1.3760x; 1.3760x over previous
//
#include <hip/hip_runtime.h>
#include <cstdint>

typedef __bf16 bf16;
typedef __attribute__((ext_vector_type(8))) __bf16 bf16x8;
typedef __attribute__((ext_vector_type(4))) float f32x4;

#define MFMA16(a, b, c) __builtin_amdgcn_mfma_f32_16x16x32_bf16(a, b, c, 0, 0, 0)

// async global->LDS, 16B per lane; LDS dest = wave-uniform base + lane*16.
__device__ __forceinline__ void async16(const bf16* g, bf16* l) {
  __builtin_amdgcn_global_load_lds(
      (const __attribute__((address_space(1))) void*)g,
      (__attribute__((address_space(3))) void*)l, 16, 0, 0);
}

__device__ __forceinline__ bf16x8 load8cvt(const float* p) {
  f32x4 a = *(const f32x4*)p;
  f32x4 b = *(const f32x4*)(p + 4);
  bf16x8 r;
  r[0] = (bf16)a[0]; r[1] = (bf16)a[1]; r[2] = (bf16)a[2]; r[3] = (bf16)a[3];
  r[4] = (bf16)b[0]; r[5] = (bf16)b[1]; r[6] = (bf16)b[2]; r[7] = (bf16)b[3];
  return r;
}

// ---------------------------------------------------------------------------
// fp32 -> bf16 elementwise convert (8 elems/thread). n must be multiple of 2048.
// ---------------------------------------------------------------------------
__global__ __launch_bounds__(256) void cvt_f32_bf16(const float* __restrict__ src,
                                                    bf16* __restrict__ dst, int n) {
  int i = (blockIdx.x * 256 + threadIdx.x) * 8;
  if (i >= n) return;
  *(bf16x8*)(dst + i) = load8cvt(src + i);
}

// ---------------------------------------------------------------------------
// C = A @ B^T + bias. Both operands bf16, both staged via global_load_lds x16.
// 128x128 tile, BK=32, 4 waves of 64x64 (m97 structure).
// bias(n) = n < nsplit ? bias0[n] : bias1[n - nsplit]  (GEMM fusion support).
// MODE 0: bf16 out only.  MODE 1: fp32 out only (stride ldo).
// MODE 2: bf16 out + fp32 out for n < nsplit (fp32 stride = nsplit).
// ---------------------------------------------------------------------------
template <int MODE>
__global__ __launch_bounds__(256) void gemm_bb(
    const bf16* __restrict__ A, int lda,
    const bf16* __restrict__ Bm, int ldb,
    const float* __restrict__ bias0, const float* __restrict__ bias1, int nsplit,
    bf16* __restrict__ outb, float* __restrict__ outf, int ldo,
    int M, int N, int K) {
  __shared__ __align__(16) bf16 As[128 * 32];
  __shared__ __align__(16) bf16 Bs[128 * 32];
  const int t = threadIdx.x;
  const int lane = t & 63, w = t >> 6;
  const int quad = lane >> 4, l15 = lane & 15;
  const int bm = blockIdx.y * 128, bn = blockIdx.x * 128;
  const int wm = (w >> 1) * 64, wn = (w & 1) * 64;

  f32x4 acc[4][4] = {};

  // staging map: thread t covers row t/4 (and +64), cols (t%4)*8..+7
  const int srow = t >> 2;
  const int scol = (t & 3) * 8;
  const bf16* Ap = A + (int64_t)(bm + srow) * lda + scol;
  const bf16* Bp = Bm + (int64_t)(bn + srow) * ldb + scol;
  bf16* ldsA0 = As + w * 512;          // wave-uniform LDS bases (16 rows/wave)
  bf16* ldsA1 = As + 2048 + w * 512;
  bf16* ldsB0 = Bs + w * 512;
  bf16* ldsB1 = Bs + 2048 + w * 512;

  for (int k0 = 0; k0 < K; k0 += 32) {
    async16(Ap + k0, ldsA0);
    async16(Ap + (int64_t)64 * lda + k0, ldsA1);
    async16(Bp + k0, ldsB0);
    async16(Bp + (int64_t)64 * ldb + k0, ldsB1);
    __syncthreads();  // drains vmcnt: all staging visible

    bf16x8 a[4], b[4];
#pragma unroll
    for (int mt = 0; mt < 4; ++mt)
      a[mt] = *(const bf16x8*)(As + (wm + mt * 16 + l15) * 32 + quad * 8);
#pragma unroll
    for (int nt = 0; nt < 4; ++nt)
      b[nt] = *(const bf16x8*)(Bs + (wn + nt * 16 + l15) * 32 + quad * 8);
#pragma unroll
    for (int mt = 0; mt < 4; ++mt)
#pragma unroll
      for (int nt = 0; nt < 4; ++nt)
        acc[mt][nt] = MFMA16(a[mt], b[nt], acc[mt][nt]);
    __syncthreads();  // all reads done before next staging
  }

  float bv[4];
#pragma unroll
  for (int nt = 0; nt < 4; ++nt) {
    int n = bn + wn + nt * 16 + l15;
    bv[nt] = (n < nsplit) ? bias0[n] : bias1[n - nsplit];
  }
#pragma unroll
  for (int mt = 0; mt < 4; ++mt)
#pragma unroll
    for (int nt = 0; nt < 4; ++nt)
#pragma unroll
      for (int r = 0; r < 4; ++r) {
        // C/D layout (m89/m91 verified): row = quad*4+r, col = lane&15
        int64_t m = bm + wm + mt * 16 + quad * 4 + r;
        int n = bn + wn + nt * 16 + l15;
        float v = acc[mt][nt][r] + bv[nt];
        if (MODE != 1) outb[m * ldo + n] = (bf16)v;
        if (MODE == 1) outf[m * (int64_t)ldo + n] = v;
        if (MODE == 2 && n < nsplit) outf[m * nsplit + n] = v;
      }
}

// ---------------------------------------------------------------------------
// k_r = rope(k @ W_KR^T + b_KR), fp32 out. K lives in fused KV buffer:
// element (token, h, d) = kmat[token*4096 + h*128 + d].
// ---------------------------------------------------------------------------
__global__ __launch_bounds__(256) void kr_rope(const bf16* __restrict__ kmat,
                                               const float* __restrict__ Wkr,
                                               const float* __restrict__ bkr,
                                               float* __restrict__ krout) {
  const int t = threadIdx.x;
  const int lane = t & 63, w = t >> 6;
  const int quad = lane >> 4, l15 = lane & 15;
  const int row0 = blockIdx.x * 64 + w * 16;

  const int rr = row0 + l15;  // flattened row = token*16 + h
  const bf16* krow = kmat + (int64_t)(rr >> 4) * 4096 + (rr & 15) * 128;
  bf16x8 af[4];
#pragma unroll
  for (int ks = 0; ks < 4; ++ks)
    af[ks] = *(const bf16x8*)(krow + ks * 32 + quad * 8);

  f32x4 acc[4] = {};
#pragma unroll
  for (int nt = 0; nt < 4; ++nt)
#pragma unroll
    for (int ks = 0; ks < 4; ++ks) {
      bf16x8 bf_ = load8cvt(Wkr + (nt * 16 + l15) * 128 + ks * 32 + quad * 8);
      acc[nt] = MFMA16(af[ks], bf_, acc[nt]);
    }

  float bv[4], fr[4];
#pragma unroll
  for (int nt = 0; nt < 4; ++nt) {
    bv[nt] = bkr[nt * 16 + l15];
    int j = ((nt & 1) * 16 + l15);  // n mod 32
    fr[nt] = exp2f(-(float)j * 0.41524101186092034f);  // 10000^(-j/32)
  }

#pragma unroll
  for (int r = 0; r < 4; ++r) {
    int row = row0 + quad * 4 + r;   // row = token*16 + h
    int pos = (row >> 4) & 1023;     // s = token mod 1024
    float val[4];
#pragma unroll
    for (int nt = 0; nt < 4; ++nt) val[nt] = acc[nt][r] + bv[nt];
#pragma unroll
    for (int nt = 0; nt < 4; ++nt) {
      int n = nt * 16 + l15;
      float ang = (float)pos * fr[nt];
      float c = cosf(ang), s = sinf(ang);
      float partner = val[nt ^ 2];  // col (n+32)%64 lives in fragment nt^2
      float o = val[nt] * c + ((nt < 2) ? -partner : partner) * s;
      krout[(int64_t)row * 64 + n] = o;
    }
  }
}

// ---------------------------------------------------------------------------
// Attention, plain softmax. Grid (16 q-tiles, 32 b*h), 4 waves/block.
// q: [2048][2048] bf16 (stride 2048). k/v: fused KV buffer, row stride 4096
// (k at col h*128+d, v pointer pre-offset by +2048).
// Vt uses XOR-swizzled key-blocks: elem(d,key) = d*72 + ((key>>3 ^ ((d>>3)&7))<<3)
// + (key&7) -> store lanes land on 8 distinct banks x2 (free).
// ---------------------------------------------------------------------------
__global__ __launch_bounds__(256) void attn_fwd(const bf16* __restrict__ q,
                                                const bf16* __restrict__ k,
                                                const bf16* __restrict__ v,
                                                bf16* __restrict__ attn) {
  const int qt = blockIdx.x, bh = blockIdx.y;
  const int b = bh >> 4, h = bh & 15;
  __shared__ __align__(16) bf16 Kt[64 * 136];   // [key][d], stride 136
  __shared__ __align__(16) bf16 Vt[128 * 72];   // [d][key-swizzled], stride 72
  __shared__ __align__(16) bf16 Pl[4][16 * 72]; // per-wave P, stride 72

  const int t = threadIdx.x;
  const int lane = t & 63, w = t >> 6;
  const int quad = lane >> 4, l15 = lane & 15;
  const int trow = b * 1024 + qt * 64 + w * 16;
  const float scale = 0.08838834764831845f;      // 1/sqrt(128)

  bf16x8 qf[4];
#pragma unroll
  for (int ks = 0; ks < 4; ++ks)
    qf[ks] = *(const bf16x8*)(q + (int64_t)(trow + l15) * 2048 + h * 128 +
                              ks * 32 + quad * 8);

  f32x4 o[8] = {};
  float lrow[4] = {0.f, 0.f, 0.f, 0.f};

  for (int kt = 0; kt < 16; ++kt) {
    __syncthreads();
#pragma unroll
    for (int r = 0; r < 4; ++r) {
      int e = (r * 256 + t) * 8;
      int key = e >> 7, dc = e & 127;
      *(bf16x8*)(Kt + key * 136 + dc) =
          *(const bf16x8*)(k + (int64_t)(b * 1024 + kt * 64 + key) * 4096 +
                           h * 128 + dc);
    }
    // V tile transposed with XOR-swizzled key-blocks
#pragma unroll
    for (int r = 0; r < 4; ++r) {
      int e = (r * 256 + t) * 8;
      int key = e >> 7, d0 = e & 127;        // d0 multiple of 8
      bf16x8 pk = *(const bf16x8*)(v + (int64_t)(b * 1024 + kt * 64 + key) * 4096 +
                                   h * 128 + d0);
      int col = (((key >> 3) ^ ((d0 >> 3) & 7)) << 3) + (key & 7);
#pragma unroll
      for (int j = 0; j < 8; ++j) Vt[(d0 + j) * 72 + col] = pk[j];
    }
    __syncthreads();

    // S = Q @ K^T  (16 x 64 per wave)
    f32x4 s[4] = {};
#pragma unroll
    for (int nt = 0; nt < 4; ++nt)
#pragma unroll
      for (int ks = 0; ks < 4; ++ks) {
        bf16x8 bfrg = *(const bf16x8*)(Kt + (nt * 16 + l15) * 136 + ks * 32 + quad * 8);
        s[nt] = MFMA16(qf[ks], bfrg, s[nt]);
      }

    // p = exp(s*scale); row sums; stash P for PV
    float rsum[4] = {0.f, 0.f, 0.f, 0.f};
#pragma unroll
    for (int nt = 0; nt < 4; ++nt)
#pragma unroll
      for (int r = 0; r < 4; ++r) {
        float p = __expf(s[nt][r] * scale);
        rsum[r] += p;
        Pl[w][(quad * 4 + r) * 72 + nt * 16 + l15] = (bf16)p;
      }
#pragma unroll
    for (int r = 0; r < 4; ++r) {
      float ssum = rsum[r];
#pragma unroll
      for (int off = 8; off >= 1; off >>= 1) ssum += __shfl_xor(ssum, off, 64);
      lrow[r] += ssum;
    }

    // O += P @ V  (B-fragment: 8 consecutive keys at fixed d -> one swizzled block)
#pragma unroll
    for (int ks = 0; ks < 2; ++ks) {
      bf16x8 afrg = *(const bf16x8*)(&Pl[w][l15 * 72 + ks * 32 + quad * 8]);
#pragma unroll
      for (int dt = 0; dt < 8; ++dt) {
        int d = dt * 16 + l15;
        int kb = ((ks * 4 + quad) ^ ((d >> 3) & 7)) << 3;
        bf16x8 bfrg = *(const bf16x8*)(Vt + d * 72 + kb);
        o[dt] = MFMA16(afrg, bfrg, o[dt]);
      }
    }
  }

#pragma unroll
  for (int dt = 0; dt < 8; ++dt)
#pragma unroll
    for (int r = 0; r < 4; ++r) {
      int64_t row = trow + quad * 4 + r;
      int col = h * 128 + dt * 16 + l15;
      attn[row * 2048 + col] = (bf16)(o[dt][r] / lrow[r]);
    }
}

// ---------------------------------------------------------------------------
extern "C" void kernel_launch(void* const* d_in, const int* in_sizes, int n_in,
                              void* d_out, int out_size, void* d_ws, size_t ws_size,
                              hipStream_t stream) {
  const float* hidden = (const float*)d_in[0];
  const float* Wdkv = (const float*)d_in[1];
  const float* bdkv = (const float*)d_in[2];
  const float* Wuk  = (const float*)d_in[3];
  const float* buk  = (const float*)d_in[4];
  const float* Wuv  = (const float*)d_in[5];
  const float* buv  = (const float*)d_in[6];
  const float* Wkr  = (const float*)d_in[7];
  const float* bkr  = (const float*)d_in[8];
  const float* Wdq  = (const float*)d_in[9];
  const float* bdq  = (const float*)d_in[10];
  const float* Wuq  = (const float*)d_in[11];
  const float* buq  = (const float*)d_in[12];
  // d_in[13], d_in[14] (W_QR_w/b): dead code in the reference.
  const float* Wo   = (const float*)d_in[15];
  const float* bo   = (const float*)d_in[16];

  // Outputs fp32.
  float* out0 = (float*)d_out;          // [2048][2048]
  float* c_kv = out0 + 4194304;         // [2048][512]
  float* k_r  = out0 + 5242880;         // [32768][64]

  // ---- workspace (25.2 MB) ----
  bf16* DKVQ = (bf16*)d_ws;             // [2048][2048]: cols 0-511 = c_kv bf16,
                                        // cols 512+ = c_q. Later reused for attn out.
  bf16* KV   = DKVQ + 4194304;          // [2048][4096]: cols 0-2047 K, 2048+ V

  // ---- transient aliases (all lifetimes verified non-overlapping) ----
  bf16* WT   = KV;                      // Wdkv+Wdq bf16 [2048][2048]; dead before KV gemm writes
  bf16* qx   = (bf16*)out0;             // [2048][2048] q (written by UQ gemm)
  bf16* hb   = qx + 4194304;            // hidden bf16; after DKVQ gemm reused for Wuq bf16
  bf16* WUKV = qx;                      // Wuk+Wuv bf16 [4096][512]; dead before UQ gemm writes qx
  bf16* Wuqb = hb;                      // Wuq bf16 [2048][1536]
  bf16* Wob  = (bf16*)k_r;              // Wo bf16 [2048][2048]; k_r written after final gemm

  // 1. hidden -> bf16
  cvt_f32_bf16<<<2048, 256, 0, stream>>>(hidden, hb, 4194304);
  // 2. W_DKV ++ W_DQ -> bf16 (stacked [2048][2048])
  cvt_f32_bf16<<<512, 256, 0, stream>>>(Wdkv, WT, 1048576);
  cvt_f32_bf16<<<1536, 256, 0, stream>>>(Wdq, WT + 1048576, 3145728);
  // 3. fused c_kv|c_q gemm: [2048][2048] = hb @ WT^T. fp32 c_kv for n<512.
  gemm_bb<2><<<dim3(16, 16), 256, 0, stream>>>(hb, 2048, WT, 2048, bdkv, bdq, 512,
                                               DKVQ, c_kv, 2048, 2048, 2048, 2048);
  // 4. W_UK ++ W_UV -> bf16 (stacked [4096][512], lives in qx region)
  cvt_f32_bf16<<<512, 256, 0, stream>>>(Wuk, WUKV, 1048576);
  cvt_f32_bf16<<<512, 256, 0, stream>>>(Wuv, WUKV + 1048576, 1048576);
  // 5. fused K|V gemm: [2048][4096] = ckv_bf @ WUKV^T (512 blocks = 2/CU)
  gemm_bb<0><<<dim3(32, 16), 256, 0, stream>>>(DKVQ, 2048, WUKV, 512, buk, buv, 2048,
                                               KV, nullptr, 4096, 2048, 4096, 512);
  // 6. W_UQ -> bf16 (hb region, hidden bf16 now dead)
  cvt_f32_bf16<<<1536, 256, 0, stream>>>(Wuq, Wuqb, 3145728);
  // 7. q gemm: qx = cq @ Wuq^T (A = DKVQ cols 512+, lda 2048)
  gemm_bb<0><<<dim3(16, 16), 256, 0, stream>>>(DKVQ + 512, 2048, Wuqb, 1536, buq, buq,
                                               2048, qx, nullptr, 2048, 2048, 2048, 1536);
  // 8. W_O -> bf16 (k_r region; k_r written afterwards)
  cvt_f32_bf16<<<2048, 256, 0, stream>>>(Wo, Wob, 4194304);
  // 9. attention -> DKVQ region (c_kv/c_q bf16 now dead)
  attn_fwd<<<dim3(16, 32), 256, 0, stream>>>(qx, KV, KV + 2048, DKVQ);
  // 10. output gemm: out0 = attn @ Wo^T (overwrites qx/hb regions, both dead)
  gemm_bb<1><<<dim3(16, 16), 256, 0, stream>>>(DKVQ, 2048, Wob, 2048, bo, bo, 2048,
                                               nullptr, out0, 2048, 2048, 2048, 2048);
  // 11. k_r rope (reads KV; overwrites Wob which is now dead)
  kr_rope<<<512, 256, 0, stream>>>(KV, Wkr, bkr, k_r);
}

// Round 2
// 326.708 us; speedup vs baseline: 1.6197x; 1.1771x over previous
//
#include <hip/hip_runtime.h>
#include <cstdint>

typedef __bf16 bf16;
typedef __attribute__((ext_vector_type(8))) __bf16 bf16x8;
typedef __attribute__((ext_vector_type(4))) float f32x4;

#define MFMA16(a, b, c) __builtin_amdgcn_mfma_f32_16x16x32_bf16(a, b, c, 0, 0, 0)

// async global->LDS, 16B per lane; LDS dest = wave-uniform base + lane*16.
__device__ __forceinline__ void async16(const bf16* g, bf16* l) {
  __builtin_amdgcn_global_load_lds(
      (const __attribute__((address_space(1))) void*)g,
      (__attribute__((address_space(3))) void*)l, 16, 0, 0);
}

__device__ __forceinline__ bf16x8 load8cvt(const float* p) {
  f32x4 a = *(const f32x4*)p;
  f32x4 b = *(const f32x4*)(p + 4);
  bf16x8 r;
  r[0] = (bf16)a[0]; r[1] = (bf16)a[1]; r[2] = (bf16)a[2]; r[3] = (bf16)a[3];
  r[4] = (bf16)b[0]; r[5] = (bf16)b[1]; r[6] = (bf16)b[2]; r[7] = (bf16)b[3];
  return r;
}

// ---------------------------------------------------------------------------
// fp32 -> bf16 elementwise convert (8 elems/thread).
// ---------------------------------------------------------------------------
__global__ __launch_bounds__(256) void cvt_f32_bf16(const float* __restrict__ src,
                                                    bf16* __restrict__ dst, int n) {
  int i = (blockIdx.x * 256 + threadIdx.x) * 8;
  if (i >= n) return;
  *(bf16x8*)(dst + i) = load8cvt(src + i);
}

// 6 converts in one launch (blockIdx.y selects segment; spare blocks exit).
__global__ __launch_bounds__(256) void cvt6(
    const float* __restrict__ s0, bf16* __restrict__ d0, int n0,
    const float* __restrict__ s1, bf16* __restrict__ d1, int n1,
    const float* __restrict__ s2, bf16* __restrict__ d2, int n2,
    const float* __restrict__ s3, bf16* __restrict__ d3, int n3,
    const float* __restrict__ s4, bf16* __restrict__ d4, int n4,
    const float* __restrict__ s5, bf16* __restrict__ d5, int n5) {
  const float* s; bf16* d; int n;
  switch (blockIdx.y) {
    case 0: s = s0; d = d0; n = n0; break;
    case 1: s = s1; d = d1; n = n1; break;
    case 2: s = s2; d = d2; n = n2; break;
    case 3: s = s3; d = d3; n = n3; break;
    case 4: s = s4; d = d4; n = n4; break;
    default: s = s5; d = d5; n = n5; break;
  }
  int i = (blockIdx.x * 256 + threadIdx.x) * 8;
  if (i >= n) return;
  *(bf16x8*)(d + i) = load8cvt(s + i);
}

// ---------------------------------------------------------------------------
// C = A @ B^T + bias. Both operands bf16, staged via global_load_lds x16.
// 128x128 tile, BK=32, 4 waves of 64x64. 2-phase prefetch: double-buffered
// LDS, next tile's loads issued BEFORE computing current -> the single
// end-of-step __syncthreads (vmcnt drain) overlaps the whole MFMA phase.
// K must be a multiple of 64 (all call sites: 2048/1536/512).
// bias(n) = n < nsplit ? bias0[n] : bias1[n - nsplit]  (GEMM fusion support).
// MODE 0: bf16 out. MODE 1: fp32 out (stride ldo). MODE 2: bf16 + fp32 n<nsplit.
// ---------------------------------------------------------------------------
template <int MODE>
__global__ __launch_bounds__(256) void gemm_bb(
    const bf16* __restrict__ A, int lda,
    const bf16* __restrict__ Bm, int ldb,
    const float* __restrict__ bias0, const float* __restrict__ bias1, int nsplit,
    bf16* __restrict__ outb, float* __restrict__ outf, int ldo,
    int M, int N, int K) {
  __shared__ __align__(16) bf16 As[2][128 * 32];
  __shared__ __align__(16) bf16 Bs[2][128 * 32];
  const int t = threadIdx.x;
  const int lane = t & 63, w = t >> 6;
  const int quad = lane >> 4, l15 = lane & 15;
  const int bm = blockIdx.y * 128, bn = blockIdx.x * 128;
  const int wm = (w >> 1) * 64, wn = (w & 1) * 64;

  f32x4 acc[4][4] = {};

  // staging map: thread t covers row t/4 (and +64), cols (t%4)*8..+7
  const int srow = t >> 2;
  const int scol = (t & 3) * 8;
  const bf16* Ap = A + (int64_t)(bm + srow) * lda + scol;
  const bf16* Bp = Bm + (int64_t)(bn + srow) * ldb + scol;

  auto STAGE = [&](int buf, int k0) {
    async16(Ap + k0, &As[buf][w * 512]);
    async16(Ap + (int64_t)64 * lda + k0, &As[buf][2048 + w * 512]);
    async16(Bp + k0, &Bs[buf][w * 512]);
    async16(Bp + (int64_t)64 * ldb + k0, &Bs[buf][2048 + w * 512]);
  };
  auto COMPUTE = [&](int buf) {
    bf16x8 a[4], bq[4];
#pragma unroll
    for (int mt = 0; mt < 4; ++mt)
      a[mt] = *(const bf16x8*)(&As[buf][(wm + mt * 16 + l15) * 32 + quad * 8]);
#pragma unroll
    for (int nt = 0; nt < 4; ++nt)
      bq[nt] = *(const bf16x8*)(&Bs[buf][(wn + nt * 16 + l15) * 32 + quad * 8]);
#pragma unroll
    for (int mt = 0; mt < 4; ++mt)
#pragma unroll
      for (int nt = 0; nt < 4; ++nt)
        acc[mt][nt] = MFMA16(a[mt], bq[nt], acc[mt][nt]);
  };

  STAGE(0, 0);
  __syncthreads();                    // tile 0 ready
  for (int k0 = 0; k0 < K; k0 += 64) {
    STAGE(1, k0 + 32);                // issue next while computing current
    COMPUTE(0);
    __syncthreads();                  // drains prefetch (overlapped) + read fence
    if (k0 + 64 < K) STAGE(0, k0 + 64);
    COMPUTE(1);
    __syncthreads();
  }

  float bv[4];
#pragma unroll
  for (int nt = 0; nt < 4; ++nt) {
    int n = bn + wn + nt * 16 + l15;
    bv[nt] = (n < nsplit) ? bias0[n] : bias1[n - nsplit];
  }
#pragma unroll
  for (int mt = 0; mt < 4; ++mt)
#pragma unroll
    for (int nt = 0; nt < 4; ++nt)
#pragma unroll
      for (int r = 0; r < 4; ++r) {
        // C/D layout (m89/m91 verified): row = quad*4+r, col = lane&15
        int64_t m = bm + wm + mt * 16 + quad * 4 + r;
        int n = bn + wn + nt * 16 + l15;
        float v = acc[mt][nt][r] + bv[nt];
        if (MODE != 1) outb[m * ldo + n] = (bf16)v;
        if (MODE == 1) outf[m * (int64_t)ldo + n] = v;
        if (MODE == 2 && n < nsplit) outf[m * nsplit + n] = v;
      }
}

// ---------------------------------------------------------------------------
// k_r = rope(k @ W_KR^T + b_KR), fp32 out. K lives in fused KV buffer:
// element (token, h, d) = kmat[token*4096 + h*128 + d].
// ---------------------------------------------------------------------------
__global__ __launch_bounds__(256) void kr_rope(const bf16* __restrict__ kmat,
                                               const float* __restrict__ Wkr,
                                               const float* __restrict__ bkr,
                                               float* __restrict__ krout) {
  const int t = threadIdx.x;
  const int lane = t & 63, w = t >> 6;
  const int quad = lane >> 4, l15 = lane & 15;
  const int row0 = blockIdx.x * 64 + w * 16;

  const int rr = row0 + l15;  // flattened row = token*16 + h
  const bf16* krow = kmat + (int64_t)(rr >> 4) * 4096 + (rr & 15) * 128;
  bf16x8 af[4];
#pragma unroll
  for (int ks = 0; ks < 4; ++ks)
    af[ks] = *(const bf16x8*)(krow + ks * 32 + quad * 8);

  f32x4 acc[4] = {};
#pragma unroll
  for (int nt = 0; nt < 4; ++nt)
#pragma unroll
    for (int ks = 0; ks < 4; ++ks) {
      bf16x8 bf_ = load8cvt(Wkr + (nt * 16 + l15) * 128 + ks * 32 + quad * 8);
      acc[nt] = MFMA16(af[ks], bf_, acc[nt]);
    }

  float bv[4], fr[4];
#pragma unroll
  for (int nt = 0; nt < 4; ++nt) {
    bv[nt] = bkr[nt * 16 + l15];
    int j = ((nt & 1) * 16 + l15);  // n mod 32
    fr[nt] = exp2f(-(float)j * 0.41524101186092034f);  // 10000^(-j/32)
  }

#pragma unroll
  for (int r = 0; r < 4; ++r) {
    int row = row0 + quad * 4 + r;   // row = token*16 + h
    int pos = (row >> 4) & 1023;     // s = token mod 1024
    float val[4];
#pragma unroll
    for (int nt = 0; nt < 4; ++nt) val[nt] = acc[nt][r] + bv[nt];
#pragma unroll
    for (int nt = 0; nt < 4; ++nt) {
      int n = nt * 16 + l15;
      float ang = (float)pos * fr[nt];
      float c = cosf(ang), s = sinf(ang);
      float partner = val[nt ^ 2];  // col (n+32)%64 lives in fragment nt^2
      float o = val[nt] * c + ((nt < 2) ? -partner : partner) * s;
      krout[(int64_t)row * 64 + n] = o;
    }
  }
}

// ---------------------------------------------------------------------------
// Attention, plain softmax. Grid (16 q-tiles, 32 b*h), 4 waves/block.
// q: [2048][2048] bf16. k/v: fused KV buffer, row stride 4096.
// T14 pipeline: K/V tile kt+1 is loaded into registers while tile kt computes;
// ds_writes at iteration top consume the regs (vmcnt wait hidden under the
// previous iteration's MFMA phase + barrier).
// Vt XOR-swizzled by key-block (round-8 fix). Pl XOR-swizzled by (row>>1)&7:
// spreads the 4 quad-groups onto disjoint bank sets (old layout was 4-way).
// lrow reduce deferred out of the kt loop (order-independent fp32 sum).
// ---------------------------------------------------------------------------
__global__ __launch_bounds__(256) void attn_fwd(const bf16* __restrict__ q,
                                                const bf16* __restrict__ k,
                                                const bf16* __restrict__ v,
                                                bf16* __restrict__ attn) {
  const int qt = blockIdx.x, bh = blockIdx.y;
  const int b = bh >> 4, h = bh & 15;
  __shared__ __align__(16) bf16 Kt[64 * 136];   // [key][d], stride 136
  __shared__ __align__(16) bf16 Vt[128 * 72];   // [d][key-swizzled], stride 72
  __shared__ __align__(16) bf16 Pl[4][16 * 72]; // per-wave P, block-swizzled

  const int t = threadIdx.x;
  const int lane = t & 63, w = t >> 6;
  const int quad = lane >> 4, l15 = lane & 15;
  const int trow = b * 1024 + qt * 64 + w * 16;
  const float scale = 0.08838834764831845f;      // 1/sqrt(128)

  bf16x8 qf[4];
#pragma unroll
  for (int ks = 0; ks < 4; ++ks)
    qf[ks] = *(const bf16x8*)(q + (int64_t)(trow + l15) * 2048 + h * 128 +
                              ks * 32 + quad * 8);

  // staging geometry: thread covers key = r*16 + (t>>4), cols (t&15)*8..+7
  const int skey = t >> 4;
  const int sd0 = (t & 15) * 8;
  const bf16* kp = k + (int64_t)b * 1024 * 4096 + h * 128 + sd0;
  const bf16* vp = v + (int64_t)b * 1024 * 4096 + h * 128 + sd0;
  const int vcol = (((skey + 0) >> 3 ^ 0) << 3);  // placeholder (per-r below)

  bf16x8 kreg[4], vreg[4];
#pragma unroll
  for (int r = 0; r < 4; ++r) {
    kreg[r] = *(const bf16x8*)(kp + (int64_t)(r * 16 + skey) * 4096);
    vreg[r] = *(const bf16x8*)(vp + (int64_t)(r * 16 + skey) * 4096);
  }

  f32x4 o[8] = {};
  float lrow[4] = {0.f, 0.f, 0.f, 0.f};

  for (int kt = 0; kt < 16; ++kt) {
    // staged regs -> LDS
#pragma unroll
    for (int r = 0; r < 4; ++r) {
      int key = r * 16 + skey;
      *(bf16x8*)(Kt + key * 136 + sd0) = kreg[r];
      int col = (((key >> 3) ^ ((sd0 >> 3) & 7)) << 3) + (key & 7);
#pragma unroll
      for (int j = 0; j < 8; ++j) Vt[(sd0 + j) * 72 + col] = vreg[r][j];
    }
    __syncthreads();

    // issue next tile's loads; latency hides under QK + softmax + PV
    if (kt + 1 < 16) {
      const bf16* kn = kp + (int64_t)(kt + 1) * 64 * 4096;
      const bf16* vn = vp + (int64_t)(kt + 1) * 64 * 4096;
#pragma unroll
      for (int r = 0; r < 4; ++r) {
        kreg[r] = *(const bf16x8*)(kn + (int64_t)(r * 16 + skey) * 4096);
        vreg[r] = *(const bf16x8*)(vn + (int64_t)(r * 16 + skey) * 4096);
      }
    }

    // S = Q @ K^T  (16 x 64 per wave)
    f32x4 s[4] = {};
    __builtin_amdgcn_s_setprio(1);
#pragma unroll
    for (int nt = 0; nt < 4; ++nt)
#pragma unroll
      for (int ks = 0; ks < 4; ++ks) {
        bf16x8 bfrg = *(const bf16x8*)(Kt + (nt * 16 + l15) * 136 + ks * 32 + quad * 8);
        s[nt] = MFMA16(qf[ks], bfrg, s[nt]);
      }
    __builtin_amdgcn_s_setprio(0);

    // p = exp(s*scale); lane-local row partials; stash P (block-swizzled)
    float rsum[4] = {0.f, 0.f, 0.f, 0.f};
#pragma unroll
    for (int nt = 0; nt < 4; ++nt)
#pragma unroll
      for (int r = 0; r < 4; ++r) {
        float p = __expf(s[nt][r] * scale);
        rsum[r] += p;
        int row = quad * 4 + r;
        int blk = (nt * 2 + (l15 >> 3)) ^ (quad * 2 + (r >> 1));
        Pl[w][row * 72 + (blk << 3) + (l15 & 7)] = (bf16)p;
      }
#pragma unroll
    for (int r = 0; r < 4; ++r) lrow[r] += rsum[r];

    // O += P @ V
    __builtin_amdgcn_s_setprio(1);
#pragma unroll
    for (int ks = 0; ks < 2; ++ks) {
      int ablk = (ks * 4 + quad) ^ (l15 >> 1);
      bf16x8 afrg = *(const bf16x8*)(&Pl[w][l15 * 72 + (ablk << 3)]);
#pragma unroll
      for (int dt = 0; dt < 8; ++dt) {
        int d = dt * 16 + l15;
        int kb = ((ks * 4 + quad) ^ ((d >> 3) & 7)) << 3;
        bf16x8 bfrg = *(const bf16x8*)(Vt + d * 72 + kb);
        o[dt] = MFMA16(afrg, bfrg, o[dt]);
      }
    }
    __builtin_amdgcn_s_setprio(0);
    __syncthreads();  // all LDS reads done before next tile's writes
  }

  float inv[4];
#pragma unroll
  for (int r = 0; r < 4; ++r) {
    float ssum = lrow[r];
#pragma unroll
    for (int off = 8; off >= 1; off >>= 1) ssum += __shfl_xor(ssum, off, 64);
    inv[r] = 1.0f / ssum;
  }
#pragma unroll
  for (int dt = 0; dt < 8; ++dt)
#pragma unroll
    for (int r = 0; r < 4; ++r) {
      int64_t row = trow + quad * 4 + r;
      int col = h * 128 + dt * 16 + l15;
      attn[row * 2048 + col] = (bf16)(o[dt][r] * inv[r]);
    }
}

// ---------------------------------------------------------------------------
extern "C" void kernel_launch(void* const* d_in, const int* in_sizes, int n_in,
                              void* d_out, int out_size, void* d_ws, size_t ws_size,
                              hipStream_t stream) {
  const float* hidden = (const float*)d_in[0];
  const float* Wdkv = (const float*)d_in[1];
  const float* bdkv = (const float*)d_in[2];
  const float* Wuk  = (const float*)d_in[3];
  const float* buk  = (const float*)d_in[4];
  const float* Wuv  = (const float*)d_in[5];
  const float* buv  = (const float*)d_in[6];
  const float* Wkr  = (const float*)d_in[7];
  const float* bkr  = (const float*)d_in[8];
  const float* Wdq  = (const float*)d_in[9];
  const float* bdq  = (const float*)d_in[10];
  const float* Wuq  = (const float*)d_in[11];
  const float* buq  = (const float*)d_in[12];
  // d_in[13], d_in[14] (W_QR_w/b): dead code in the reference.
  const float* Wo   = (const float*)d_in[15];
  const float* bo   = (const float*)d_in[16];

  // Outputs fp32.
  float* out0 = (float*)d_out;          // [2048][2048]
  float* c_kv = out0 + 4194304;         // [2048][512]
  float* k_r  = out0 + 5242880;         // [32768][64]

  // ---- workspace (25.2 MB) ----
  bf16* DKVQ = (bf16*)d_ws;             // [2048][2048]: cols 0-511 = c_kv bf16,
                                        // cols 512+ = c_q. Later reused for attn out.
  bf16* KV   = DKVQ + 4194304;          // [2048][4096]: cols 0-2047 K, 2048+ V

  // ---- transient aliases (lifetimes verified non-overlapping) ----
  bf16* WT   = KV;                      // Wdkv+Wdq bf16 [2048][2048]; dead before KV gemm writes
  bf16* qx   = (bf16*)out0;             // [2048][2048] q (written by UQ gemm)
  bf16* hb   = qx + 4194304;            // hidden bf16; after DKVQ gemm reused for Wuq bf16
  bf16* WUKV = qx;                      // Wuk+Wuv bf16 [4096][512]; dead before UQ gemm writes qx
  bf16* Wuqb = hb;                      // Wuq bf16 [2048][1536]
  bf16* Wob  = (bf16*)k_r;              // Wo bf16 [2048][2048]; k_r written after final gemm

  // 1. all leading converts in one launch: hidden, Wdkv, Wdq, Wuk, Wuv, Wo
  cvt6<<<dim3(2048, 6), 256, 0, stream>>>(
      hidden, hb, 4194304,
      Wdkv, WT, 1048576,
      Wdq, WT + 1048576, 3145728,
      Wuk, WUKV, 1048576,
      Wuv, WUKV + 1048576, 1048576,
      Wo, Wob, 4194304);
  // 2. fused c_kv|c_q gemm: [2048][2048] = hb @ WT^T. fp32 c_kv for n<512.
  gemm_bb<2><<<dim3(16, 16), 256, 0, stream>>>(hb, 2048, WT, 2048, bdkv, bdq, 512,
                                               DKVQ, c_kv, 2048, 2048, 2048, 2048);
  // 3. W_UQ -> bf16 (hb region; hidden bf16 consumed by step 2)
  cvt_f32_bf16<<<1536, 256, 0, stream>>>(Wuq, Wuqb, 3145728);
  // 4. fused K|V gemm: [2048][4096] = ckv_bf @ WUKV^T (512 blocks = 2/CU)
  gemm_bb<0><<<dim3(32, 16), 256, 0, stream>>>(DKVQ, 2048, WUKV, 512, buk, buv, 2048,
                                               KV, nullptr, 4096, 2048, 4096, 512);
  // 5. q gemm: qx = cq @ Wuq^T (A = DKVQ cols 512+, lda 2048)
  gemm_bb<0><<<dim3(16, 16), 256, 0, stream>>>(DKVQ + 512, 2048, Wuqb, 1536, buq, buq,
                                               2048, qx, nullptr, 2048, 2048, 2048, 1536);
  // 6. attention -> DKVQ region (c_kv/c_q bf16 now dead)
  attn_fwd<<<dim3(16, 32), 256, 0, stream>>>(qx, KV, KV + 2048, DKVQ);
  // 7. output gemm: out0 = attn @ Wo^T (overwrites qx/hb regions, both dead)
  gemm_bb<1><<<dim3(16, 16), 256, 0, stream>>>(DKVQ, 2048, Wob, 2048, bo, bo, 2048,
                                               nullptr, out0, 2048, 2048, 2048, 2048);
  // 8. k_r rope (reads KV; overwrites Wob which is now dead)
  kr_rope<<<512, 256, 0, stream>>>(KV, Wkr, bkr, k_r);
}

// Round 3
// 310.248 us; speedup vs baseline: 1.7056x; 1.0531x over previous
//
#include <hip/hip_runtime.h>
#include <cstdint>

typedef __bf16 bf16;
typedef __attribute__((ext_vector_type(8))) __bf16 bf16x8;
typedef __attribute__((ext_vector_type(4))) float f32x4;

#define MFMA16(a, b, c) __builtin_amdgcn_mfma_f32_16x16x32_bf16(a, b, c, 0, 0, 0)

// async global->LDS, 16B per lane; LDS dest = wave-uniform base + lane*16.
__device__ __forceinline__ void async16(const bf16* g, bf16* l) {
  __builtin_amdgcn_global_load_lds(
      (const __attribute__((address_space(1))) void*)g,
      (__attribute__((address_space(3))) void*)l, 16, 0, 0);
}

__device__ __forceinline__ bf16x8 load8cvt(const float* p) {
  f32x4 a = *(const f32x4*)p;
  f32x4 b = *(const f32x4*)(p + 4);
  bf16x8 r;
  r[0] = (bf16)a[0]; r[1] = (bf16)a[1]; r[2] = (bf16)a[2]; r[3] = (bf16)a[3];
  r[4] = (bf16)b[0]; r[5] = (bf16)b[1]; r[6] = (bf16)b[2]; r[7] = (bf16)b[3];
  return r;
}

// ---------------------------------------------------------------------------
// fp32 -> bf16 elementwise convert (8 elems/thread).
// ---------------------------------------------------------------------------
__global__ __launch_bounds__(256) void cvt_f32_bf16(const float* __restrict__ src,
                                                    bf16* __restrict__ dst, int n) {
  int i = (blockIdx.x * 256 + threadIdx.x) * 8;
  if (i >= n) return;
  *(bf16x8*)(dst + i) = load8cvt(src + i);
}

// 6 converts in one launch (blockIdx.y selects segment; spare blocks exit).
__global__ __launch_bounds__(256) void cvt6(
    const float* __restrict__ s0, bf16* __restrict__ d0, int n0,
    const float* __restrict__ s1, bf16* __restrict__ d1, int n1,
    const float* __restrict__ s2, bf16* __restrict__ d2, int n2,
    const float* __restrict__ s3, bf16* __restrict__ d3, int n3,
    const float* __restrict__ s4, bf16* __restrict__ d4, int n4,
    const float* __restrict__ s5, bf16* __restrict__ d5, int n5) {
  const float* s; bf16* d; int n;
  switch (blockIdx.y) {
    case 0: s = s0; d = d0; n = n0; break;
    case 1: s = s1; d = d1; n = n1; break;
    case 2: s = s2; d = d2; n = n2; break;
    case 3: s = s3; d = d3; n = n3; break;
    case 4: s = s4; d = d4; n = n4; break;
    default: s = s5; d = d5; n = n5; break;
  }
  int i = (blockIdx.x * 256 + threadIdx.x) * 8;
  if (i >= n) return;
  *(bf16x8*)(d + i) = load8cvt(s + i);
}

// ---------------------------------------------------------------------------
// C = A @ B^T + bias. Both operands bf16, staged via global_load_lds x16.
// 128x64 tile (grid 2-4 blocks/CU at these shapes), BK=32, 4 waves of 64x32.
// Counted-vmcnt 2-phase (m201 pattern): prefetch loads stay in flight across
// raw s_barrier; only the CURRENT buffer's 3 loads are waited (vmcnt(3)).
// K must be a multiple of 64 (call sites: 2048/1536/512).
// bias(n) = n < nsplit ? bias0[n] : bias1[n - nsplit]  (GEMM fusion support).
// MODE 0: bf16 out. MODE 1: fp32 out (stride ldo). MODE 2: bf16 + fp32 n<nsplit.
// ---------------------------------------------------------------------------
template <int MODE>
__global__ __launch_bounds__(256) void gemm_bb(
    const bf16* __restrict__ A, int lda,
    const bf16* __restrict__ Bm, int ldb,
    const float* __restrict__ bias0, const float* __restrict__ bias1, int nsplit,
    bf16* __restrict__ outb, float* __restrict__ outf, int ldo,
    int M, int N, int K) {
  __shared__ __align__(16) bf16 As[2][128 * 32];
  __shared__ __align__(16) bf16 Bs[2][64 * 32];
  const int t = threadIdx.x;
  const int lane = t & 63, w = t >> 6;
  const int quad = lane >> 4, l15 = lane & 15;

  // XCD-aware chunked swizzle (all call-site grids have nwg % 8 == 0).
  const int nwg = gridDim.x * gridDim.y;
  const int id = blockIdx.y * gridDim.x + blockIdx.x;
  const int sw = (id & 7) * (nwg >> 3) + (id >> 3);
  const int bm = (sw / gridDim.x) * 128, bn = (sw % gridDim.x) * 64;

  const int wm = (w >> 1) * 64, wn = (w & 1) * 32;

  f32x4 acc[4][2] = {};

  // staging map: thread t covers row t/4, cols (t%4)*8..+7
  const int srow = t >> 2;
  const int scol = (t & 3) * 8;
  const bf16* Ap = A + (int64_t)(bm + srow) * lda + scol;
  const bf16* Bp = Bm + (int64_t)(bn + srow) * ldb + scol;

  auto STAGE = [&](int buf, int k0) {
    async16(Ap + k0, &As[buf][w * 512]);                       // A rows 0..63
    async16(Ap + (int64_t)64 * lda + k0, &As[buf][2048 + w * 512]);  // A rows 64..127
    async16(Bp + k0, &Bs[buf][w * 512]);                       // B rows 0..63
  };
  auto COMPUTE = [&](int buf) {
    bf16x8 a[4], bq[2];
#pragma unroll
    for (int mt = 0; mt < 4; ++mt)
      a[mt] = *(const bf16x8*)(&As[buf][(wm + mt * 16 + l15) * 32 + quad * 8]);
#pragma unroll
    for (int nt = 0; nt < 2; ++nt)
      bq[nt] = *(const bf16x8*)(&Bs[buf][(wn + nt * 16 + l15) * 32 + quad * 8]);
#pragma unroll
    for (int mt = 0; mt < 4; ++mt)
#pragma unroll
      for (int nt = 0; nt < 2; ++nt)
        acc[mt][nt] = MFMA16(a[mt], bq[nt], acc[mt][nt]);
  };

  STAGE(0, 0);  // 3 loads in flight
  for (int k0 = 0; k0 < K; k0 += 64) {
    STAGE(1, k0 + 32);  // 6 in flight
    // wait own 3 oldest (buf0) done, then sync all waves; buf1 stays in flight
    asm volatile("s_waitcnt vmcnt(3)\n\ts_barrier" ::: "memory");
    COMPUTE(0);
    // all LDS reads retired before anyone overwrites buf0
    asm volatile("s_waitcnt lgkmcnt(0)\n\ts_barrier" ::: "memory");
    if (k0 + 64 < K) {
      STAGE(0, k0 + 64);
      asm volatile("s_waitcnt vmcnt(3)\n\ts_barrier" ::: "memory");
    } else {
      asm volatile("s_waitcnt vmcnt(0)\n\ts_barrier" ::: "memory");
    }
    COMPUTE(1);
    asm volatile("s_waitcnt lgkmcnt(0)\n\ts_barrier" ::: "memory");
  }

  float bv[2];
#pragma unroll
  for (int nt = 0; nt < 2; ++nt) {
    int n = bn + wn + nt * 16 + l15;
    bv[nt] = (n < nsplit) ? bias0[n] : bias1[n - nsplit];
  }
#pragma unroll
  for (int mt = 0; mt < 4; ++mt)
#pragma unroll
    for (int nt = 0; nt < 2; ++nt)
#pragma unroll
      for (int r = 0; r < 4; ++r) {
        // C/D layout (m89/m91 verified): row = quad*4+r, col = lane&15
        int64_t m = bm + wm + mt * 16 + quad * 4 + r;
        int n = bn + wn + nt * 16 + l15;
        float v = acc[mt][nt][r] + bv[nt];
        if (MODE != 1) outb[m * ldo + n] = (bf16)v;
        if (MODE == 1) outf[m * (int64_t)ldo + n] = v;
        if (MODE == 2 && n < nsplit) outf[m * nsplit + n] = v;
      }
}

// ---------------------------------------------------------------------------
// k_r = rope(k @ W_KR^T + b_KR), fp32 out. K lives in fused KV buffer:
// element (token, h, d) = kmat[token*4096 + h*128 + d].
// ---------------------------------------------------------------------------
__global__ __launch_bounds__(256) void kr_rope(const bf16* __restrict__ kmat,
                                               const float* __restrict__ Wkr,
                                               const float* __restrict__ bkr,
                                               float* __restrict__ krout) {
  const int t = threadIdx.x;
  const int lane = t & 63, w = t >> 6;
  const int quad = lane >> 4, l15 = lane & 15;
  const int row0 = blockIdx.x * 64 + w * 16;

  const int rr = row0 + l15;  // flattened row = token*16 + h
  const bf16* krow = kmat + (int64_t)(rr >> 4) * 4096 + (rr & 15) * 128;
  bf16x8 af[4];
#pragma unroll
  for (int ks = 0; ks < 4; ++ks)
    af[ks] = *(const bf16x8*)(krow + ks * 32 + quad * 8);

  f32x4 acc[4] = {};
#pragma unroll
  for (int nt = 0; nt < 4; ++nt)
#pragma unroll
    for (int ks = 0; ks < 4; ++ks) {
      bf16x8 bf_ = load8cvt(Wkr + (nt * 16 + l15) * 128 + ks * 32 + quad * 8);
      acc[nt] = MFMA16(af[ks], bf_, acc[nt]);
    }

  float bv[4], fr[4];
#pragma unroll
  for (int nt = 0; nt < 4; ++nt) {
    bv[nt] = bkr[nt * 16 + l15];
    int j = ((nt & 1) * 16 + l15);  // n mod 32
    fr[nt] = exp2f(-(float)j * 0.41524101186092034f);  // 10000^(-j/32)
  }

#pragma unroll
  for (int r = 0; r < 4; ++r) {
    int row = row0 + quad * 4 + r;   // row = token*16 + h
    int pos = (row >> 4) & 1023;     // s = token mod 1024
    float val[4];
#pragma unroll
    for (int nt = 0; nt < 4; ++nt) val[nt] = acc[nt][r] + bv[nt];
#pragma unroll
    for (int nt = 0; nt < 4; ++nt) {
      int n = nt * 16 + l15;
      float ang = (float)pos * fr[nt];
      float c = cosf(ang), s = sinf(ang);
      float partner = val[nt ^ 2];  // col (n+32)%64 lives in fragment nt^2
      float o = val[nt] * c + ((nt < 2) ? -partner : partner) * s;
      krout[(int64_t)row * 64 + n] = o;
    }
  }
}

// ---------------------------------------------------------------------------
// Attention, plain softmax. Grid (16 q-tiles, 32 b*h), 4 waves/block.
// q: [2048][2048] bf16. k/v: fused KV buffer, row stride 4096.
// T14 pipeline: K/V tile kt+1 loaded into registers while tile kt computes.
// Vt XOR-swizzled by key-block; Pl block-swizzled; lrow reduce deferred.
// ---------------------------------------------------------------------------
__global__ __launch_bounds__(256) void attn_fwd(const bf16* __restrict__ q,
                                                const bf16* __restrict__ k,
                                                const bf16* __restrict__ v,
                                                bf16* __restrict__ attn) {
  const int qt = blockIdx.x, bh = blockIdx.y;
  const int b = bh >> 4, h = bh & 15;
  __shared__ __align__(16) bf16 Kt[64 * 136];   // [key][d], stride 136
  __shared__ __align__(16) bf16 Vt[128 * 72];   // [d][key-swizzled], stride 72
  __shared__ __align__(16) bf16 Pl[4][16 * 72]; // per-wave P, block-swizzled

  const int t = threadIdx.x;
  const int lane = t & 63, w = t >> 6;
  const int quad = lane >> 4, l15 = lane & 15;
  const int trow = b * 1024 + qt * 64 + w * 16;
  const float scale = 0.08838834764831845f;      // 1/sqrt(128)

  bf16x8 qf[4];
#pragma unroll
  for (int ks = 0; ks < 4; ++ks)
    qf[ks] = *(const bf16x8*)(q + (int64_t)(trow + l15) * 2048 + h * 128 +
                              ks * 32 + quad * 8);

  // staging geometry: thread covers key = r*16 + (t>>4), cols (t&15)*8..+7
  const int skey = t >> 4;
  const int sd0 = (t & 15) * 8;
  const bf16* kp = k + (int64_t)b * 1024 * 4096 + h * 128 + sd0;
  const bf16* vp = v + (int64_t)b * 1024 * 4096 + h * 128 + sd0;

  bf16x8 kreg[4], vreg[4];
#pragma unroll
  for (int r = 0; r < 4; ++r) {
    kreg[r] = *(const bf16x8*)(kp + (int64_t)(r * 16 + skey) * 4096);
    vreg[r] = *(const bf16x8*)(vp + (int64_t)(r * 16 + skey) * 4096);
  }

  f32x4 o[8] = {};
  float lrow[4] = {0.f, 0.f, 0.f, 0.f};

  for (int kt = 0; kt < 16; ++kt) {
    // staged regs -> LDS
#pragma unroll
    for (int r = 0; r < 4; ++r) {
      int key = r * 16 + skey;
      *(bf16x8*)(Kt + key * 136 + sd0) = kreg[r];
      int col = (((key >> 3) ^ ((sd0 >> 3) & 7)) << 3) + (key & 7);
#pragma unroll
      for (int j = 0; j < 8; ++j) Vt[(sd0 + j) * 72 + col] = vreg[r][j];
    }
    __syncthreads();

    // issue next tile's loads; latency hides under QK + softmax + PV
    if (kt + 1 < 16) {
      const bf16* kn = kp + (int64_t)(kt + 1) * 64 * 4096;
      const bf16* vn = vp + (int64_t)(kt + 1) * 64 * 4096;
#pragma unroll
      for (int r = 0; r < 4; ++r) {
        kreg[r] = *(const bf16x8*)(kn + (int64_t)(r * 16 + skey) * 4096);
        vreg[r] = *(const bf16x8*)(vn + (int64_t)(r * 16 + skey) * 4096);
      }
    }

    // S = Q @ K^T  (16 x 64 per wave)
    f32x4 s[4] = {};
    __builtin_amdgcn_s_setprio(1);
#pragma unroll
    for (int nt = 0; nt < 4; ++nt)
#pragma unroll
      for (int ks = 0; ks < 4; ++ks) {
        bf16x8 bfrg = *(const bf16x8*)(Kt + (nt * 16 + l15) * 136 + ks * 32 + quad * 8);
        s[nt] = MFMA16(qf[ks], bfrg, s[nt]);
      }
    __builtin_amdgcn_s_setprio(0);

    // p = exp(s*scale); lane-local row partials; stash P (block-swizzled)
    float rsum[4] = {0.f, 0.f, 0.f, 0.f};
#pragma unroll
    for (int nt = 0; nt < 4; ++nt)
#pragma unroll
      for (int r = 0; r < 4; ++r) {
        float p = __expf(s[nt][r] * scale);
        rsum[r] += p;
        int row = quad * 4 + r;
        int blk = (nt * 2 + (l15 >> 3)) ^ (quad * 2 + (r >> 1));
        Pl[w][row * 72 + (blk << 3) + (l15 & 7)] = (bf16)p;
      }
#pragma unroll
    for (int r = 0; r < 4; ++r) lrow[r] += rsum[r];

    // O += P @ V
    __builtin_amdgcn_s_setprio(1);
#pragma unroll
    for (int ks = 0; ks < 2; ++ks) {
      int ablk = (ks * 4 + quad) ^ (l15 >> 1);
      bf16x8 afrg = *(const bf16x8*)(&Pl[w][l15 * 72 + (ablk << 3)]);
#pragma unroll
      for (int dt = 0; dt < 8; ++dt) {
        int d = dt * 16 + l15;
        int kb = ((ks * 4 + quad) ^ ((d >> 3) & 7)) << 3;
        bf16x8 bfrg = *(const bf16x8*)(Vt + d * 72 + kb);
        o[dt] = MFMA16(afrg, bfrg, o[dt]);
      }
    }
    __builtin_amdgcn_s_setprio(0);
    __syncthreads();  // all LDS reads done before next tile's writes
  }

  float inv[4];
#pragma unroll
  for (int r = 0; r < 4; ++r) {
    float ssum = lrow[r];
#pragma unroll
    for (int off = 8; off >= 1; off >>= 1) ssum += __shfl_xor(ssum, off, 64);
    inv[r] = 1.0f / ssum;
  }
#pragma unroll
  for (int dt = 0; dt < 8; ++dt)
#pragma unroll
    for (int r = 0; r < 4; ++r) {
      int64_t row = trow + quad * 4 + r;
      int col = h * 128 + dt * 16 + l15;
      attn[row * 2048 + col] = (bf16)(o[dt][r] * inv[r]);
    }
}

// ---------------------------------------------------------------------------
extern "C" void kernel_launch(void* const* d_in, const int* in_sizes, int n_in,
                              void* d_out, int out_size, void* d_ws, size_t ws_size,
                              hipStream_t stream) {
  const float* hidden = (const float*)d_in[0];
  const float* Wdkv = (const float*)d_in[1];
  const float* bdkv = (const float*)d_in[2];
  const float* Wuk  = (const float*)d_in[3];
  const float* buk  = (const float*)d_in[4];
  const float* Wuv  = (const float*)d_in[5];
  const float* buv  = (const float*)d_in[6];
  const float* Wkr  = (const float*)d_in[7];
  const float* bkr  = (const float*)d_in[8];
  const float* Wdq  = (const float*)d_in[9];
  const float* bdq  = (const float*)d_in[10];
  const float* Wuq  = (const float*)d_in[11];
  const float* buq  = (const float*)d_in[12];
  // d_in[13], d_in[14] (W_QR_w/b): dead code in the reference.
  const float* Wo   = (const float*)d_in[15];
  const float* bo   = (const float*)d_in[16];

  // Outputs fp32.
  float* out0 = (float*)d_out;          // [2048][2048]
  float* c_kv = out0 + 4194304;         // [2048][512]
  float* k_r  = out0 + 5242880;         // [32768][64]

  // ---- workspace (25.2 MB) ----
  bf16* DKVQ = (bf16*)d_ws;             // [2048][2048]: cols 0-511 = c_kv bf16,
                                        // cols 512+ = c_q. Later reused for attn out.
  bf16* KV   = DKVQ + 4194304;          // [2048][4096]: cols 0-2047 K, 2048+ V

  // ---- transient aliases (lifetimes verified non-overlapping) ----
  bf16* WT   = KV;                      // Wdkv+Wdq bf16 [2048][2048]; dead before KV gemm writes
  bf16* qx   = (bf16*)out0;             // [2048][2048] q (written by UQ gemm)
  bf16* hb   = qx + 4194304;            // hidden bf16; after DKVQ gemm reused for Wuq bf16
  bf16* WUKV = qx;                      // Wuk+Wuv bf16 [4096][512]; dead before UQ gemm writes qx
  bf16* Wuqb = hb;                      // Wuq bf16 [2048][1536]
  bf16* Wob  = (bf16*)k_r;              // Wo bf16 [2048][2048]; k_r written after final gemm

  // 1. all leading converts in one launch: hidden, Wdkv, Wdq, Wuk, Wuv, Wo
  cvt6<<<dim3(2048, 6), 256, 0, stream>>>(
      hidden, hb, 4194304,
      Wdkv, WT, 1048576,
      Wdq, WT + 1048576, 3145728,
      Wuk, WUKV, 1048576,
      Wuv, WUKV + 1048576, 1048576,
      Wo, Wob, 4194304);
  // 2. fused c_kv|c_q gemm: [2048][2048] = hb @ WT^T. fp32 c_kv for n<512.
  gemm_bb<2><<<dim3(32, 16), 256, 0, stream>>>(hb, 2048, WT, 2048, bdkv, bdq, 512,
                                               DKVQ, c_kv, 2048, 2048, 2048, 2048);
  // 3. W_UQ -> bf16 (hb region; hidden bf16 consumed by step 2)
  cvt_f32_bf16<<<1536, 256, 0, stream>>>(Wuq, Wuqb, 3145728);
  // 4. fused K|V gemm: [2048][4096] = ckv_bf @ WUKV^T (1024 blocks = 4/CU)
  gemm_bb<0><<<dim3(64, 16), 256, 0, stream>>>(DKVQ, 2048, WUKV, 512, buk, buv, 2048,
                                               KV, nullptr, 4096, 2048, 4096, 512);
  // 5. q gemm: qx = cq @ Wuq^T (A = DKVQ cols 512+, lda 2048)
  gemm_bb<0><<<dim3(32, 16), 256, 0, stream>>>(DKVQ + 512, 2048, Wuqb, 1536, buq, buq,
                                               2048, qx, nullptr, 2048, 2048, 2048, 1536);
  // 6. attention -> DKVQ region (c_kv/c_q bf16 now dead)
  attn_fwd<<<dim3(16, 32), 256, 0, stream>>>(qx, KV, KV + 2048, DKVQ);
  // 7. output gemm: out0 = attn @ Wo^T (overwrites qx/hb regions, both dead)
  gemm_bb<1><<<dim3(32, 16), 256, 0, stream>>>(DKVQ, 2048, Wob, 2048, bo, bo, 2048,
                                               nullptr, out0, 2048, 2048, 2048, 2048);
  // 8. k_r rope (reads KV; overwrites Wob which is now dead)
  kr_rope<<<512, 256, 0, stream>>>(KV, Wkr, bkr, k_r);
}